// Round 12
// baseline (364.505 us; speedup 1.0000x reference)
//
#include <hip/hip_runtime.h>
#include <hip/hip_cooperative_groups.h>
#include <math.h>

namespace cg = cooperative_groups;

#define NN 4096
#define CBLK 8               // worker blocks (fallback exchange protocol)
#define NPB (NN / CBLK)      // 512 threads per sim block
#define GRID_SIM 128         // candidate blocks; >=16 on some XCD by pigeonhole
#define SLOT_STRIDE 16       // ulls per line: 128 B -- ONE writer per line
#define CTRL_BYTES 4096
#define CTRL_ULLS 512
#define TRAJ_CAP 2032        // max steps the uniform-trajectory path supports
#define TRAJ_BYTES 8192      // 2032 floats + status + Qacc[6] + badc + mieb

typedef unsigned long long ull;

// ---------------------------------------------------------------------------
// Session ledger (structural facts, all HW-verified):
//  R1: multi-writer 128B lines -> L2 dirty thrash to HBM (2.65x). one writer/line.
//  R2: removing the per-step wave-parking barrier -> VMEM spin storm.
//  R4: sc0 asm = SE scope only; agent scope structural.
//  R5/R7: exchange line-count axis exhausted; 8 block lines optimal.
//  R6: 968us fallback champion; ~1 agent RTT/step, plumbing shadowed.
//  R8: data saturates (V rails uniformly, gates NaN -> V=0 forever);
//      probe+certificate+broadcast, absmax 0.
//  R9: probe NaN early-exit; ~38us per dispatch boundary measured.
//  R10: grid-parallel memory work in the 1-block probe = 8 GB/s disaster.
//  R11: 241us = 88us kernels + 4x38us boundaries. col_partial stuck at
//      ~2.6 TB/s regardless of CH/occupancy (axis dead).
//  R12 (this): ONE cooperative kernel (A: partial, B: grid-parallel
//      reduce+Qg+uniformity via per-block atomics, C: serial trajectory
//      only, D: broadcast) + tiny status-guard fallback kernel. If coop
//      launch errors, host falls back to the R11 4-dispatch sequence.
// ---------------------------------------------------------------------------

// ---------------- DPP wave64 reduction helpers (HW-validated R2-R11) --------
template <int DC, int RM>
__device__ __forceinline__ float dppmov(float x) {
    return __int_as_float(
        __builtin_amdgcn_update_dpp(0, __float_as_int(x), DC, RM, 0xf, true));
}
__device__ __forceinline__ float wave_sum63(float x) {
    x += dppmov<0x111, 0xf>(x);   // row_shr:1
    x += dppmov<0x112, 0xf>(x);   // row_shr:2
    x += dppmov<0x114, 0xf>(x);   // row_shr:4
    x += dppmov<0x118, 0xf>(x);   // row_shr:8
    x += dppmov<0x142, 0xa>(x);   // row_bcast:15 -> rows 1,3
    x += dppmov<0x143, 0xc>(x);   // row_bcast:31 -> rows 2,3
    return x;                     // lane 63 holds the 64-lane sum
}
__device__ __forceinline__ float wave_max63(float x) {   // nonneg inputs
    x = fmaxf(x, dppmov<0x111, 0xf>(x));
    x = fmaxf(x, dppmov<0x112, 0xf>(x));
    x = fmaxf(x, dppmov<0x114, 0xf>(x));
    x = fmaxf(x, dppmov<0x118, 0xf>(x));
    x = fmaxf(x, dppmov<0x142, 0xa>(x));
    x = fmaxf(x, dppmov<0x143, 0xc>(x));
    return x;
}
__device__ __forceinline__ float dpp_sum8(float x) {
    x += dppmov<0x111, 0xf>(x);
    x += dppmov<0x112, 0xf>(x);
    x += dppmov<0x114, 0xf>(x);
    return x;
}
__device__ __forceinline__ float rdlane(float x, int l) {
    return __int_as_float(__builtin_amdgcn_readlane(__float_as_int(x), l));
}

// ---------------- shared device body: the serial uniform trajectory ---------
// EXACT R6/R11 gate arithmetic + certificate + NaN early exit. Runs on one
// wave; lane0 writes traj, lanes fill tail. Returns ok.
__device__ __forceinline__ int run_trajectory(
    const float* Qacc, float MIe, int steps, int lane,
    float* __restrict__ traj)
{
    float Qg[6];
#pragma unroll
    for (int t = 0; t < 6; ++t) Qg[t] = Qacc[t];
    const float CE1g = -70.0f * Qg[1];
    const float CE2g = -90.0f * Qg[2];

    const float tau[6] = { 2.0f, 5.0f, 10.0f, 100.0f, 50.0f, 30.0f };
    const float sgn[6] = { -1.0f, 1.0f, 1.0f, -1.0f, -1.0f, -1.0f };
    float dec[6], sD[6];
#pragma unroll
    for (int t = 0; t < 6; ++t) { dec[t] = 1.0f - 0.01f / tau[t]; sD[t] = sgn[t] * dec[t]; }

    float vu = 0.0f, m = 0.0f, h = 0.0f, n = 0.0f;
    int ok = 1;
    int kend = steps;

    for (int k = 0; k < steps; ++k) {
        float Cg = sD[5] * Qg[5];
        Cg = fmaf(sD[4], Qg[4], Cg);
        Cg = fmaf(sD[3], Qg[3], Cg);
        Cg = fmaf(sD[2], Qg[2], Cg);
        Cg = fmaf(sD[1], Qg[1], Cg);
        Cg = fmaf(sD[0], Qg[0], Cg);
        const float corrg = fmaf(sD[1], CE1g, sD[2] * CE2g);
        const float S = fmaf(vu, Cg, -corrg);

        const float v = vu;
        const float a1 = 2.5f - 0.1f * v;
        const float X = __expf(a1);
        const float am = a1 * __builtin_amdgcn_rcpf(X - 1.0f);
        const float bm = 4.0f * __expf(v * (-1.0f / 18.0f));
        const float ah = 0.07f * __expf(v * (-1.0f / 20.0f));
        const float bh = __builtin_amdgcn_rcpf(fmaf(1.6487212707001281f, X, 1.0f));
        const float a5 = 0.1f - 0.01f * v;
        const float an = a5 * __builtin_amdgcn_rcpf(fmaf(0.2231301601484298f, X, -1.0f));
        const float bn = 0.125f * __expf(v * (-1.0f / 80.0f));
        const float mm = m + 0.01f * (am * (1.0f - m) - bm * m);
        const float hh = h + 0.01f * (ah * (1.0f - h) - bh * h);
        const float nn = n + 0.01f * (an * (1.0f - n) - bn * n);
        m = mm; h = hh; n = nn;
        const float INa = ((120.0f * ((mm * mm) * mm)) * hh) * (v - 50.0f);
        const float n2 = nn * nn;
        const float IK = (36.0f * (n2 * n2)) * (v + 77.0f);
        const float IL = 0.3f * (v + 54.387f);
        const float Bu = ((0.0f - INa) - IK) - IL;
        const float t = vu + 0.01f * (Bu + S);

        float vn;
        if (t != t) {
            vn = 0.0f;                       // NaN -> nan_to_num -> 0 (exact)
        } else if (t > 1e30f) {
            vn = 100.0f;
        } else if (t < -1e30f) {
            vn = -100.0f;
        } else {
            const float slack = 0.01f * MIe + 0.01f +
                1e-4f * (fabsf(t) + fabsf(vu) +
                         0.01f * (fabsf(S) + fabsf(INa) + fabsf(IK)));
            if (t - slack > 100.0f)       vn = 100.0f;
            else if (t + slack < -100.0f) vn = -100.0f;
            else { ok = 0; break; }          // ambiguous -> exchange fallback
        }
        if (lane == 0) traj[k] = vn;
        vu = vn;

        // gate NaN persists forever -> all later V = 0 for every neuron. Exact.
        if ((m != m) || (h != h) || (n != n)) { kend = k + 1; break; }

#pragma unroll
        for (int t6 = 0; t6 < 6; ++t6) sD[t6] *= dec[t6];
    }
    if (ok) {
        for (int r = kend + lane; r < steps; r += 64) traj[r] = 0.0f;
    }
    return ok;
}

// ---------------- R12 cooperative mega-kernel -------------------------------
// grid (16, CH) x 256 threads, all co-resident (19.5KB LDS -> 8 blocks/CU).
// aux layout after traj: [status int][Qacc 6f][badc u32][mieb u32]
__global__ __launch_bounds__(256) void hh_coop_k(
    const float* __restrict__ Iext, const float* __restrict__ V0,
    const float* __restrict__ m0, const float* __restrict__ h0,
    const float* __restrict__ n0, const float* __restrict__ s0,
    const float* __restrict__ W, const int* __restrict__ Ty,
    const int* __restrict__ Tp, ull* __restrict__ ctrl,
    float* __restrict__ part, float* __restrict__ cols,
    float* __restrict__ traj, int* __restrict__ status,
    int CH, float* __restrict__ out)
{
#pragma clang fp contract(off)
    cg::grid_group grid = cg::this_grid();
    const int tid = threadIdx.x;     // 0..255
    const int wv = tid >> 6;         // 0..3
    const int lane = tid & 63;
    const int flat = blockIdx.y * gridDim.x + blockIdx.x;
    const int nflat = gridDim.x * gridDim.y;

    int* statusI = status;
    float* Qacc = (float*)(status + 1);
    unsigned* badc = (unsigned*)(Qacc + 6);
    unsigned* mieb = badc + 1;

    __shared__ float red[3][64][25];   // phase A reduce (19.2 KB)
    __shared__ float redb[4], redm[4];

    // ================= phase A: col_partial + accumulator zero =============
    if (flat == 0) {
        ctrl[tid] = 0ULL; ctrl[tid + 256] = 0ULL;
        if (tid < 6) Qacc[tid] = 0.f;
        if (tid == 6) *badc = 0u;
        if (tid == 7) *mieb = 0u;
        if (tid == 8) *statusI = 0;
    }
    {
        const int chunkRows = NN / CH;
        const int rpw = chunkRows >> 2;
        const int j4 = (blockIdx.x * 64 + lane) * 4;
        const int c = blockIdx.y;
        const size_t i0 = (size_t)c * (size_t)chunkRows + (size_t)wv * (size_t)rpw;

        float a[6][4];
#pragma unroll
        for (int t = 0; t < 6; ++t)
#pragma unroll
            for (int r = 0; r < 4; ++r) a[t][r] = 0.f;

#pragma unroll 4
        for (size_t i = i0; i < i0 + (size_t)rpw; ++i) {
            const size_t off = i * NN + j4;
            const float4 w = *(const float4*)(W + off);
            const int4 t = *(const int4*)(Ty + off);
            const float wv4[4] = { w.x, w.y, w.z, w.w };
            const int tv[4] = { t.x, t.y, t.z, t.w };
#pragma unroll
            for (int r = 0; r < 4; ++r) {
                a[0][r] += (tv[r] == 1) ? wv4[r] : 0.f;
                a[1][r] += (tv[r] == 2) ? wv4[r] : 0.f;
                a[2][r] += (tv[r] == 3) ? wv4[r] : 0.f;
                a[3][r] += (tv[r] == 4) ? wv4[r] : 0.f;
                a[4][r] += (tv[r] == 5) ? wv4[r] : 0.f;
                a[5][r] += (tv[r] == 6) ? wv4[r] : 0.f;
            }
        }

        if (wv > 0) {
#pragma unroll
            for (int t = 0; t < 6; ++t)
#pragma unroll
                for (int r = 0; r < 4; ++r)
                    red[wv - 1][lane][t * 4 + r] = a[t][r];
        }
        __syncthreads();
        if (wv == 0) {
#pragma unroll
            for (int w = 0; w < 3; ++w)
#pragma unroll
                for (int t = 0; t < 6; ++t)
#pragma unroll
                    for (int r = 0; r < 4; ++r)
                        a[t][r] += red[w][lane][t * 4 + r];
            const size_t base = ((size_t)c * 6) * NN + (size_t)j4;
#pragma unroll
            for (int t = 0; t < 6; ++t)
                *(float4*)(part + base + (size_t)t * NN) =
                    make_float4(a[t][0], a[t][1], a[t][2], a[t][3]);
        }
    }
    grid.sync();

    // ========== phase B: cols reduce + Qg + uniformity (grid-parallel) ======
    // B1: each 256-chunk of the 6*NN cols space lies within ONE type t
    //     (256 | 4096), so one atomicAdd(Qacc[t]) per block-chunk.
    for (int base = flat * 256; base < 6 * NN; base += nflat * 256) {
        const int idx = base + tid;
        float sv;
        if (CH > 1) {
            float s = 0.f;
            for (int c = 0; c < CH; ++c) s += part[(size_t)c * 6 * NN + idx];
            cols[idx] = s;
            sv = s;
        } else {
            sv = cols[idx];
        }
        float v = 0.1f * s0[idx] * sv;
        v = wave_sum63(v);
        if (lane == 63) redb[wv] = v;
        __syncthreads();
        if (tid == 0) {
            const float s = redb[0] + redb[1] + redb[2] + redb[3];
            atomicAdd(&Qacc[base >> 12], s);
        }
        __syncthreads();
    }
    // B2: uniformity count + max|Ie|
    for (int base = flat * 256; base < NN; base += nflat * 256) {
        const int i = base + tid;
        float bad = ((V0[i] != 0.f) ? 1.f : 0.f) + ((m0[i] != 0.f) ? 1.f : 0.f)
                  + ((h0[i] != 0.f) ? 1.f : 0.f) + ((n0[i] != 0.f) ? 1.f : 0.f);
        float aie = fabsf(Iext[i]);
        bad = wave_sum63(bad);
        aie = wave_max63(aie);
        if (lane == 63) { redb[wv] = bad; redm[wv] = aie; }
        __syncthreads();
        if (tid == 0) {
            const float b = redb[0] + redb[1] + redb[2] + redb[3];
            const float mx = fmaxf(fmaxf(redm[0], redm[1]), fmaxf(redm[2], redm[3]));
            if (b != 0.f) atomicAdd(badc, 1u);
            atomicMax(mieb, __float_as_uint(mx));   // nonneg: bits monotonic
        }
        __syncthreads();
    }
    grid.sync();

    // ================= phase C: serial trajectory (block 0, wave 0) =========
    if (flat == 0) {
        const int steps = Tp[0] * 100;
        const bool okg = (*badc == 0u) && (steps <= TRAJ_CAP);
        if (!okg) {
            if (tid == 0)
                __hip_atomic_store(statusI, 0, __ATOMIC_RELAXED,
                                   __HIP_MEMORY_SCOPE_AGENT);
        } else if (wv == 0) {
            const float MIe = __uint_as_float(*mieb);
            const int ok = run_trajectory(Qacc, MIe, steps, lane, traj);
            if (lane == 0)
                __hip_atomic_store(statusI, ok, __ATOMIC_RELAXED,
                                   __HIP_MEMORY_SCOPE_AGENT);
        }
    }
    grid.sync();

    // ================= phase D: broadcast write (if certified) ==============
    const int st = __hip_atomic_load(statusI, __ATOMIC_RELAXED,
                                     __HIP_MEMORY_SCOPE_AGENT);
    if (st == 1) {
        const int steps = Tp[0] * 100;
        for (int r = flat; r < steps; r += nflat) {
            const float vv = traj[r];
            const float4 val = make_float4(vv, vv, vv, vv);
            float4* row = (float4*)(out + (size_t)r * NN);
            row[tid] = val;
            row[tid + 256] = val;
            row[tid + 512] = val;
            row[tid + 768] = val;
        }
    }
    // st == 0: hh_fallback_k (always enqueued after) runs the R6 exchange sim
}

// ---------------- guard + R6-champion fallback ------------------------------
// Always enqueued after the coop kernel; exits immediately when certified.
__global__ __launch_bounds__(NPB) void hh_fallback_k(
    const float* __restrict__ Iext, const float* __restrict__ V0,
    const float* __restrict__ m0, const float* __restrict__ h0,
    const float* __restrict__ n0, const float* __restrict__ s0,
    const float* __restrict__ cols, const int* __restrict__ Tp,
    ull* __restrict__ ctrl, const int* __restrict__ status,
    float* __restrict__ out)
{
#pragma clang fp contract(off)
    if (__hip_atomic_load(status, __ATOMIC_RELAXED,
                          __HIP_MEMORY_SCOPE_AGENT) == 1)
        return;

    const int steps = Tp[0] * 100;
    const int tid = threadIdx.x;
    const int wave = tid >> 6;
    const int lane = tid & 63;

    __shared__ int sRank; __shared__ ull sKey, sChosen;
    __shared__ ull wtag[2][8];
    __shared__ float binit1[8], binit2[8];

    if (tid == 0) {
        // HW_REG_XCC_ID = hwreg 20, bits [3:0]  [measured: learn_hip m09]
        const int xid = (int)(__builtin_amdgcn_s_getreg((3 << 11) | 20)) & 7;
        const ull r = atomicAdd(&ctrl[(size_t)xid * SLOT_STRIDE], 1ULL);
        if (r == (ull)(CBLK - 1))
            atomicCAS(&ctrl[128], 0ULL, (ull)(xid + 1));
        ull ch;
        do {
            ch = __hip_atomic_load(&ctrl[128],
                                   __ATOMIC_RELAXED, __HIP_MEMORY_SCOPE_AGENT);
        } while (ch == 0ULL);
        sRank = (int)r; sKey = (ull)(xid + 1); sChosen = ch;
    }
    __syncthreads();
    const int b = sRank;
    if (sKey != sChosen || b >= CBLK) return;

    const int j = b * NPB + tid;
    ull* const slots = ctrl + 144;

    const float tau[6] = { 2.0f, 5.0f, 10.0f, 100.0f, 50.0f, 30.0f };
    const float sgn[6] = { -1.0f, 1.0f, 1.0f, -1.0f, -1.0f, -1.0f };
    float dec[6], sD[6];
#pragma unroll
    for (int t = 0; t < 6; ++t) { dec[t] = 1.0f - 0.01f / tau[t]; sD[t] = sgn[t]; }

    if (tid < 16) wtag[tid >> 3][tid & 7] = 0ULL;

    float V = V0[j], m = m0[j], h = h0[j], n = n0[j], Ie = Iext[j];
    float q[6];
#pragma unroll
    for (int t = 0; t < 6; ++t)
        q[t] = 0.1f * s0[(size_t)t * NN + j] * cols[(size_t)t * NN + j];

    {
        const float b1 = wave_sum63(q[1]);
        const float b2 = wave_sum63(q[2]);
        if (lane == 63) { binit1[wave] = b1; binit2[wave] = b2; }
    }
    __syncthreads();
    float CE1 = 0.f, CE2 = 0.f;
    if (wave == 0) {
        const float s1 = dpp_sum8((lane < 8) ? binit1[lane] : 0.f);
        const float s2 = dpp_sum8((lane < 8) ? binit2[lane] : 0.f);
        CE1 = -70.0f * rdlane(s1, 7);
        CE2 = -90.0f * rdlane(s2, 7);
    }
    __syncthreads();

#pragma unroll
    for (int t = 0; t < 6; ++t) sD[t] *= dec[t];
    float w6 = sD[5] * q[5];
    w6 = fmaf(sD[4], q[4], w6);
    w6 = fmaf(sD[3], q[3], w6);
    w6 = fmaf(sD[2], q[2], w6);
    w6 = fmaf(sD[1], q[1], w6);
    w6 = fmaf(sD[0], q[0], w6);
    float corr = fmaf(sD[1], CE1, sD[2] * CE2);

    float* op = out + j;

    for (int k = 0; k < steps; ++k) {
        const unsigned tag = (unsigned)(k + 1);
        const int par = (k & 1);

        const float x = w6 * V;
        const float xs = wave_sum63(x);
        if (lane == 63)
            __hip_atomic_store(&wtag[par][wave],
                               ((ull)tag << 32) | (ull)__float_as_uint(xs),
                               __ATOMIC_RELAXED, __HIP_MEMORY_SCOPE_WORKGROUP);
        __builtin_amdgcn_sched_barrier(0);

        if (wave == 0) {
            ull got = 0;
            if (lane < 8) {
                do {
                    got = __hip_atomic_load(&wtag[par][lane],
                                            __ATOMIC_RELAXED,
                                            __HIP_MEMORY_SCOPE_WORKGROUP);
                } while ((unsigned)(got >> 32) != tag);
            }
            float p = dpp_sum8((lane < 8) ? __uint_as_float((unsigned)got) : 0.f);
            if (lane == 7) {
                p = p - corr;
                const ull packed = ((ull)tag << 32) | (ull)__float_as_uint(p);
                __hip_atomic_store(&slots[(size_t)(par * CBLK + b) * SLOT_STRIDE],
                                   packed, __ATOMIC_RELAXED,
                                   __HIP_MEMORY_SCOPE_AGENT);
            }
        }
        __builtin_amdgcn_sched_barrier(0);
        __builtin_amdgcn_s_barrier();
        __builtin_amdgcn_sched_barrier(0);

        const float v = V;
        const float a1 = 2.5f - 0.1f * v;
        const float X = __expf(a1);
        const float am = a1 * __builtin_amdgcn_rcpf(X - 1.0f);
        const float bm = 4.0f * __expf(v * (-1.0f / 18.0f));
        const float ah = 0.07f * __expf(v * (-1.0f / 20.0f));
        const float bh = __builtin_amdgcn_rcpf(
            fmaf(1.6487212707001281f, X, 1.0f));
        const float a5 = 0.1f - 0.01f * v;
        const float an = a5 * __builtin_amdgcn_rcpf(
            fmaf(0.2231301601484298f, X, -1.0f));
        const float bn = 0.125f * __expf(v * (-1.0f / 80.0f));
        const float mm = m + 0.01f * (am * (1.0f - m) - bm * m);
        const float hh = h + 0.01f * (ah * (1.0f - h) - bh * h);
        const float nn = n + 0.01f * (an * (1.0f - n) - bn * n);
        m = mm; h = hh; n = nn;
        const float INa = ((120.0f * ((mm * mm) * mm)) * hh) * (v - 50.0f);
        const float n2 = nn * nn;
        const float IK = (36.0f * (n2 * n2)) * (v + 77.0f);
        const float IL = 0.3f * (v + 54.387f);
        const float base = ((Ie - INa) - IK) - IL;

#pragma unroll
        for (int t = 0; t < 6; ++t) sD[t] *= dec[t];
        float w6n = sD[5] * q[5];
        w6n = fmaf(sD[4], q[4], w6n);
        w6n = fmaf(sD[3], q[3], w6n);
        w6n = fmaf(sD[2], q[2], w6n);
        w6n = fmaf(sD[1], q[1], w6n);
        w6n = fmaf(sD[0], q[0], w6n);
        const float corrn = fmaf(sD[1], CE1, sD[2] * CE2);
        __builtin_amdgcn_sched_barrier(0);

        ull got = 0;
        if (lane < 8) {
            do {
                got = __hip_atomic_load(&slots[(size_t)(par * CBLK + lane) * SLOT_STRIDE],
                                        __ATOMIC_RELAXED, __HIP_MEMORY_SCOPE_AGENT);
            } while ((unsigned)(got >> 32) != tag);
        }
        float val = dpp_sum8((lane < 8) ? __uint_as_float((unsigned)got) : 0.f);
        const float S = rdlane(val, 7);

        const float u = V + 0.01f * (base + S);
        V = (u != u) ? 0.0f : fminf(fmaxf(u, -100.0f), 100.0f);
        *op = V; op += NN;
        w6 = w6n; corr = corrn;
    }
}

// ============ R11 proven kernels (used only if coop launch errors) ==========
__global__ __launch_bounds__(256) void col_partial_k(
    const float* __restrict__ W, const int* __restrict__ Ty,
    float* __restrict__ part, int chunkRows)
{
    const int tid = threadIdx.x;
    const int wv = tid >> 6;
    const int lane = tid & 63;
    const int j4 = (blockIdx.x * 64 + lane) * 4;
    const int c = blockIdx.y;
    const int rpw = chunkRows >> 2;
    const size_t i0 = (size_t)c * (size_t)chunkRows + (size_t)wv * (size_t)rpw;

    float a[6][4];
#pragma unroll
    for (int t = 0; t < 6; ++t)
#pragma unroll
        for (int r = 0; r < 4; ++r) a[t][r] = 0.f;

#pragma unroll 4
    for (size_t i = i0; i < i0 + (size_t)rpw; ++i) {
        const size_t off = i * NN + j4;
        const float4 w = *(const float4*)(W + off);
        const int4 t = *(const int4*)(Ty + off);
        const float wv4[4] = { w.x, w.y, w.z, w.w };
        const int tv[4] = { t.x, t.y, t.z, t.w };
#pragma unroll
        for (int r = 0; r < 4; ++r) {
            a[0][r] += (tv[r] == 1) ? wv4[r] : 0.f;
            a[1][r] += (tv[r] == 2) ? wv4[r] : 0.f;
            a[2][r] += (tv[r] == 3) ? wv4[r] : 0.f;
            a[3][r] += (tv[r] == 4) ? wv4[r] : 0.f;
            a[4][r] += (tv[r] == 5) ? wv4[r] : 0.f;
            a[5][r] += (tv[r] == 6) ? wv4[r] : 0.f;
        }
    }

    __shared__ float red[3][64][25];
    if (wv > 0) {
#pragma unroll
        for (int t = 0; t < 6; ++t)
#pragma unroll
            for (int r = 0; r < 4; ++r)
                red[wv - 1][lane][t * 4 + r] = a[t][r];
    }
    __syncthreads();
    if (wv == 0) {
#pragma unroll
        for (int w = 0; w < 3; ++w)
#pragma unroll
            for (int t = 0; t < 6; ++t)
#pragma unroll
                for (int r = 0; r < 4; ++r)
                    a[t][r] += red[w][lane][t * 4 + r];
        const size_t base = ((size_t)c * 6) * NN + (size_t)j4;
#pragma unroll
        for (int t = 0; t < 6; ++t)
            *(float4*)(part + base + (size_t)t * NN) =
                make_float4(a[t][0], a[t][1], a[t][2], a[t][3]);
    }
}

__global__ __launch_bounds__(256) void col_reduce_k(
    const float* __restrict__ part, float* __restrict__ cols, int CH)
{
    const int idx = blockIdx.x * 256 + threadIdx.x;
    float s = 0.f;
    for (int c = 0; c < CH; ++c) s += part[(size_t)c * 6 * NN + idx];
    cols[idx] = s;
}

__global__ __launch_bounds__(512) void hh_probe_k(
    const float* __restrict__ Iext, const float* __restrict__ V0,
    const float* __restrict__ m0, const float* __restrict__ h0,
    const float* __restrict__ n0, const float* __restrict__ s0,
    const float* __restrict__ cols, ull* __restrict__ ctrl,
    const int* __restrict__ Tp,
    float* __restrict__ traj, int* __restrict__ status)
{
#pragma clang fp contract(off)
    const int tid = threadIdx.x, wave = tid >> 6, lane = tid & 63;
    const int steps = Tp[0] * 100;

    if (tid < CTRL_ULLS) ctrl[tid] = 0ULL;

    __shared__ float red[8];
    __shared__ float sQg[6], sMIe, sBad;

    float bad = 0.f, mie = 0.f;
    for (int i = tid; i < NN; i += 512) {
        bad += (V0[i] != 0.f) ? 1.f : 0.f;
        bad += (m0[i] != 0.f) ? 1.f : 0.f;
        bad += (h0[i] != 0.f) ? 1.f : 0.f;
        bad += (n0[i] != 0.f) ? 1.f : 0.f;
        mie = fmaxf(mie, fabsf(Iext[i]));
    }
    bad = wave_sum63(bad);
    if (lane == 63) red[wave] = bad;
    __syncthreads();
    if (tid == 0) { float s = 0.f; for (int w = 0; w < 8; ++w) s += red[w]; sBad = s; }
    __syncthreads();
    mie = wave_max63(mie);
    if (lane == 63) red[wave] = mie;
    __syncthreads();
    if (tid == 0) { float s = 0.f; for (int w = 0; w < 8; ++w) s = fmaxf(s, red[w]); sMIe = s; }
    __syncthreads();
    for (int t = 0; t < 6; ++t) {
        float acc = 0.f;
        for (int i = tid; i < NN; i += 512)
            acc += 0.1f * s0[(size_t)t * NN + i] * cols[(size_t)t * NN + i];
        acc = wave_sum63(acc);
        if (lane == 63) red[wave] = acc;
        __syncthreads();
        if (tid == 0) { float s = 0.f; for (int w = 0; w < 8; ++w) s += red[w]; sQg[t] = s; }
        __syncthreads();
    }

    if (sBad != 0.f || steps > TRAJ_CAP) {
        if (tid == 0) *status = 0;
        return;
    }
    if (wave != 0) return;

    const int ok = run_trajectory(sQg, sMIe, steps, lane, traj);
    if (lane == 0) *status = ok;
}

__global__ __launch_bounds__(NPB) void hh_sim_k(
    const float* __restrict__ Iext, const float* __restrict__ V0,
    const float* __restrict__ m0, const float* __restrict__ h0,
    const float* __restrict__ n0, const float* __restrict__ s0,
    const float* __restrict__ cols, const int* __restrict__ Tp,
    ull* __restrict__ ctrl, const float* __restrict__ traj,
    const int* __restrict__ status, float* __restrict__ out)
{
#pragma clang fp contract(off)
    const int steps = Tp[0] * 100;
    const int tid = threadIdx.x;

    if (*status == 1) {
        for (int r = blockIdx.x; r < steps; r += GRID_SIM) {
            const float vv = traj[r];
            const float4 val = make_float4(vv, vv, vv, vv);
            float4* p = (float4*)(out + (size_t)r * NN + (size_t)tid * 8);
            p[0] = val; p[1] = val;
        }
        return;
    }
    // fallback: delegate to the same code path as hh_fallback_k by inlining
    // the R6 exchange here would duplicate; instead just run it via the
    // fallback kernel body (copied): to keep this error-path simple and
    // proven, replicate the R6 loop.
    const int wave = tid >> 6;
    const int lane = tid & 63;

    __shared__ int sRank; __shared__ ull sKey, sChosen;
    __shared__ ull wtag[2][8];
    __shared__ float binit1[8], binit2[8];

    if (tid == 0) {
        const int xid = (int)(__builtin_amdgcn_s_getreg((3 << 11) | 20)) & 7;
        const ull r = atomicAdd(&ctrl[(size_t)xid * SLOT_STRIDE], 1ULL);
        if (r == (ull)(CBLK - 1))
            atomicCAS(&ctrl[128], 0ULL, (ull)(xid + 1));
        ull ch;
        do {
            ch = __hip_atomic_load(&ctrl[128],
                                   __ATOMIC_RELAXED, __HIP_MEMORY_SCOPE_AGENT);
        } while (ch == 0ULL);
        sRank = (int)r; sKey = (ull)(xid + 1); sChosen = ch;
    }
    __syncthreads();
    const int b = sRank;
    if (sKey != sChosen || b >= CBLK) return;

    const int j = b * NPB + tid;
    ull* const slots = ctrl + 144;

    const float tau[6] = { 2.0f, 5.0f, 10.0f, 100.0f, 50.0f, 30.0f };
    const float sgn[6] = { -1.0f, 1.0f, 1.0f, -1.0f, -1.0f, -1.0f };
    float dec[6], sD[6];
#pragma unroll
    for (int t = 0; t < 6; ++t) { dec[t] = 1.0f - 0.01f / tau[t]; sD[t] = sgn[t]; }

    if (tid < 16) wtag[tid >> 3][tid & 7] = 0ULL;

    float V = V0[j], m = m0[j], h = h0[j], n = n0[j], Ie = Iext[j];
    float q[6];
#pragma unroll
    for (int t = 0; t < 6; ++t)
        q[t] = 0.1f * s0[(size_t)t * NN + j] * cols[(size_t)t * NN + j];

    {
        const float b1 = wave_sum63(q[1]);
        const float b2 = wave_sum63(q[2]);
        if (lane == 63) { binit1[wave] = b1; binit2[wave] = b2; }
    }
    __syncthreads();
    float CE1 = 0.f, CE2 = 0.f;
    if (wave == 0) {
        const float s1 = dpp_sum8((lane < 8) ? binit1[lane] : 0.f);
        const float s2 = dpp_sum8((lane < 8) ? binit2[lane] : 0.f);
        CE1 = -70.0f * rdlane(s1, 7);
        CE2 = -90.0f * rdlane(s2, 7);
    }
    __syncthreads();

#pragma unroll
    for (int t = 0; t < 6; ++t) sD[t] *= dec[t];
    float w6 = sD[5] * q[5];
    w6 = fmaf(sD[4], q[4], w6);
    w6 = fmaf(sD[3], q[3], w6);
    w6 = fmaf(sD[2], q[2], w6);
    w6 = fmaf(sD[1], q[1], w6);
    w6 = fmaf(sD[0], q[0], w6);
    float corr = fmaf(sD[1], CE1, sD[2] * CE2);

    float* op = out + j;

    for (int k = 0; k < steps; ++k) {
        const unsigned tag = (unsigned)(k + 1);
        const int par = (k & 1);

        const float x = w6 * V;
        const float xs = wave_sum63(x);
        if (lane == 63)
            __hip_atomic_store(&wtag[par][wave],
                               ((ull)tag << 32) | (ull)__float_as_uint(xs),
                               __ATOMIC_RELAXED, __HIP_MEMORY_SCOPE_WORKGROUP);
        __builtin_amdgcn_sched_barrier(0);

        if (wave == 0) {
            ull got = 0;
            if (lane < 8) {
                do {
                    got = __hip_atomic_load(&wtag[par][lane],
                                            __ATOMIC_RELAXED,
                                            __HIP_MEMORY_SCOPE_WORKGROUP);
                } while ((unsigned)(got >> 32) != tag);
            }
            float p = dpp_sum8((lane < 8) ? __uint_as_float((unsigned)got) : 0.f);
            if (lane == 7) {
                p = p - corr;
                const ull packed = ((ull)tag << 32) | (ull)__float_as_uint(p);
                __hip_atomic_store(&slots[(size_t)(par * CBLK + b) * SLOT_STRIDE],
                                   packed, __ATOMIC_RELAXED,
                                   __HIP_MEMORY_SCOPE_AGENT);
            }
        }
        __builtin_amdgcn_sched_barrier(0);
        __builtin_amdgcn_s_barrier();
        __builtin_amdgcn_sched_barrier(0);

        const float v = V;
        const float a1 = 2.5f - 0.1f * v;
        const float X = __expf(a1);
        const float am = a1 * __builtin_amdgcn_rcpf(X - 1.0f);
        const float bm = 4.0f * __expf(v * (-1.0f / 18.0f));
        const float ah = 0.07f * __expf(v * (-1.0f / 20.0f));
        const float bh = __builtin_amdgcn_rcpf(
            fmaf(1.6487212707001281f, X, 1.0f));
        const float a5 = 0.1f - 0.01f * v;
        const float an = a5 * __builtin_amdgcn_rcpf(
            fmaf(0.2231301601484298f, X, -1.0f));
        const float bn = 0.125f * __expf(v * (-1.0f / 80.0f));
        const float mm = m + 0.01f * (am * (1.0f - m) - bm * m);
        const float hh = h + 0.01f * (ah * (1.0f - h) - bh * h);
        const float nn = n + 0.01f * (an * (1.0f - n) - bn * n);
        m = mm; h = hh; n = nn;
        const float INa = ((120.0f * ((mm * mm) * mm)) * hh) * (v - 50.0f);
        const float n2 = nn * nn;
        const float IK = (36.0f * (n2 * n2)) * (v + 77.0f);
        const float IL = 0.3f * (v + 54.387f);
        const float base = ((Ie - INa) - IK) - IL;

#pragma unroll
        for (int t = 0; t < 6; ++t) sD[t] *= dec[t];
        float w6n = sD[5] * q[5];
        w6n = fmaf(sD[4], q[4], w6n);
        w6n = fmaf(sD[3], q[3], w6n);
        w6n = fmaf(sD[2], q[2], w6n);
        w6n = fmaf(sD[1], q[1], w6n);
        w6n = fmaf(sD[0], q[0], w6n);
        const float corrn = fmaf(sD[1], CE1, sD[2] * CE2);
        __builtin_amdgcn_sched_barrier(0);

        ull got = 0;
        if (lane < 8) {
            do {
                got = __hip_atomic_load(&slots[(size_t)(par * CBLK + lane) * SLOT_STRIDE],
                                        __ATOMIC_RELAXED, __HIP_MEMORY_SCOPE_AGENT);
            } while ((unsigned)(got >> 32) != tag);
        }
        float val = dpp_sum8((lane < 8) ? __uint_as_float((unsigned)got) : 0.f);
        const float S = rdlane(val, 7);

        const float u = V + 0.01f * (base + S);
        V = (u != u) ? 0.0f : fminf(fmaxf(u, -100.0f), 100.0f);
        *op = V; op += NN;
        w6 = w6n; corr = corrn;
    }
}

// ---------------- single-block fallback (tiny workspace) --------------------
__global__ __launch_bounds__(1024) void hh_sim_single(
    const float* __restrict__ Iext, const float* __restrict__ V0,
    const float* __restrict__ m0, const float* __restrict__ h0,
    const float* __restrict__ n0, const float* __restrict__ s0,
    const float* __restrict__ colsg, const int* __restrict__ Tp,
    const float* __restrict__ W, const int* __restrict__ Ty,
    int computeCols, float* __restrict__ out)
{
#pragma clang fp contract(off)
    const int tid = threadIdx.x;
    const int j0 = tid * 4;
    const int steps = Tp[0] * 100;

    const float tau[6] = { 2.0f, 5.0f, 10.0f, 100.0f, 50.0f, 30.0f };
    const float sgn[6] = { -1.0f, 1.0f, 1.0f, -1.0f, -1.0f, -1.0f };
    float dec[6], sD[6];
#pragma unroll
    for (int t = 0; t < 6; ++t) { dec[t] = 1.0f - 0.01f / tau[t]; sD[t] = sgn[t]; }

    float q[6][4];
    if (computeCols) {
        float acc[6][4];
#pragma unroll
        for (int t = 0; t < 6; ++t)
#pragma unroll
            for (int r = 0; r < 4; ++r) acc[t][r] = 0.f;
        for (int i = 0; i < NN; ++i) {
            const size_t rowo = (size_t)i * NN + (size_t)j0;
#pragma unroll
            for (int r = 0; r < 4; ++r) {
                const float w = W[rowo + r];
                const int t = Ty[rowo + r];
                acc[0][r] += (t == 1) ? w : 0.f;
                acc[1][r] += (t == 2) ? w : 0.f;
                acc[2][r] += (t == 3) ? w : 0.f;
                acc[3][r] += (t == 4) ? w : 0.f;
                acc[4][r] += (t == 5) ? w : 0.f;
                acc[5][r] += (t == 6) ? w : 0.f;
            }
        }
#pragma unroll
        for (int t = 0; t < 6; ++t)
#pragma unroll
            for (int r = 0; r < 4; ++r)
                q[t][r] = 0.1f * s0[(size_t)t * NN + j0 + r] * acc[t][r];
    } else {
#pragma unroll
        for (int t = 0; t < 6; ++t)
#pragma unroll
            for (int r = 0; r < 4; ++r)
                q[t][r] = 0.1f * s0[(size_t)t * NN + j0 + r] *
                          colsg[(size_t)t * NN + j0 + r];
    }

    float V[4], m[4], h[4], n[4], Ie[4];
#pragma unroll
    for (int r = 0; r < 4; ++r) {
        V[r] = V0[j0 + r]; m[r] = m0[j0 + r]; h[r] = h0[j0 + r];
        n[r] = n0[j0 + r]; Ie[r] = Iext[j0 + r];
    }

    __shared__ float wsum[2][16];
    __shared__ float Bsh[2];
    {
        float b1 = 0.f, b2 = 0.f;
#pragma unroll
        for (int r = 0; r < 4; ++r) { b1 += q[1][r]; b2 += q[2][r]; }
#pragma unroll
        for (int off = 32; off > 0; off >>= 1) {
            b1 += __shfl_down(b1, off);
            b2 += __shfl_down(b2, off);
        }
        if ((tid & 63) == 0) { wsum[0][tid >> 6] = b1; wsum[1][tid >> 6] = b2; }
        __syncthreads();
        if (tid == 0) {
            float s1 = 0.f, s2 = 0.f;
            for (int w2 = 0; w2 < 16; ++w2) { s1 += wsum[0][w2]; s2 += wsum[1][w2]; }
            Bsh[0] = s1; Bsh[1] = s2;
        }
        __syncthreads();
    }
    const float CE1 = -70.0f * Bsh[0];
    const float CE2 = -90.0f * Bsh[1];
    __syncthreads();

    for (int k = 0; k < steps; ++k) {
#pragma unroll
        for (int t = 0; t < 6; ++t) sD[t] *= dec[t];
        float p = 0.f;
#pragma unroll
        for (int r = 0; r < 4; ++r) {
            float w = sD[5] * q[5][r];
            w = fmaf(sD[4], q[4][r], w);
            w = fmaf(sD[3], q[3][r], w);
            w = fmaf(sD[2], q[2][r], w);
            w = fmaf(sD[1], q[1][r], w);
            w = fmaf(sD[0], q[0][r], w);
            p = fmaf(w, V[r], p);
        }
#pragma unroll
        for (int off = 32; off > 0; off >>= 1) p += __shfl_down(p, off);
        const int par = k & 1;
        if ((tid & 63) == 0) wsum[par][tid >> 6] = p;
        __syncthreads();
        float psum = 0.f;
#pragma unroll
        for (int w2 = 0; w2 < 16; ++w2) psum += wsum[par][w2];
        const float S = psum - fmaf(sD[1], CE1, sD[2] * CE2);

#pragma unroll
        for (int r = 0; r < 4; ++r) {
            const float v = V[r];
            const float Ipre = Ie[r] + S;
            const float a1 = 2.5f - 0.1f * v;
            const float X = __expf(a1);
            const float am = a1 * __builtin_amdgcn_rcpf(X - 1.0f);
            const float bm = 4.0f * __expf(v * (-1.0f / 18.0f));
            const float ah = 0.07f * __expf(v * (-1.0f / 20.0f));
            const float bh = __builtin_amdgcn_rcpf(fmaf(1.6487212707001281f, X, 1.0f));
            const float a5 = 0.1f - 0.01f * v;
            const float an = a5 * __builtin_amdgcn_rcpf(fmaf(0.2231301601484298f, X, -1.0f));
            const float bn = 0.125f * __expf(v * (-1.0f / 80.0f));
            const float mm = m[r] + 0.01f * (am * (1.0f - m[r]) - bm * m[r]);
            const float hh = h[r] + 0.01f * (ah * (1.0f - h[r]) - bh * h[r]);
            const float nn = n[r] + 0.01f * (an * (1.0f - n[r]) - bn * n[r]);
            m[r] = mm; h[r] = hh; n[r] = nn;
            const float INa = ((120.0f * ((mm * mm) * mm)) * hh) * (v - 50.0f);
            const float n2 = nn * nn;
            const float IK = (36.0f * (n2 * n2)) * (v + 77.0f);
            const float IL = 0.3f * (v + 54.387f);
            const float u = v + 0.01f * (((Ipre - INa) - IK) - IL);
            V[r] = (u != u) ? 0.0f : fminf(fmaxf(u, -100.0f), 100.0f);
        }
        *(float4*)(out + (size_t)k * NN + j0) =
            make_float4(V[0], V[1], V[2], V[3]);
    }
}

extern "C" void kernel_launch(void* const* d_in, const int* in_sizes, int n_in,
                              void* d_out, int out_size, void* d_ws, size_t ws_size,
                              hipStream_t stream)
{
    const float* Iext = (const float*)d_in[0];
    const float* W    = (const float*)d_in[1];
    const float* V0   = (const float*)d_in[2];
    const float* m0   = (const float*)d_in[3];
    const float* h0   = (const float*)d_in[4];
    const float* n0   = (const float*)d_in[5];
    const float* s0   = (const float*)d_in[6];
    const int*   Ty   = (const int*)d_in[7];
    const int*   Tp   = (const int*)d_in[8];
    float* out = (float*)d_out;

    // ws layout: [ctrl 4096][cols 6*NN f32][traj+aux 8192][part CH*6*NN f32]
    ull*   ctrl = (ull*)d_ws;
    float* cols = (float*)((char*)d_ws + CTRL_BYTES);
    float* traj = (float*)((char*)cols + (size_t)6 * NN * sizeof(float));
    int*   status = (int*)(traj + TRAJ_CAP);
    float* part = (float*)((char*)traj + TRAJ_BYTES);

    int CH = 0;
    const int tiers[2] = { 32, 8 };
    const size_t fixed = CTRL_BYTES + TRAJ_BYTES + (size_t)6 * NN * sizeof(float);
    for (int i = 0; i < 2; ++i) {
        const size_t need = fixed + (size_t)tiers[i] * 6 * NN * sizeof(float);
        if (ws_size >= need) { CH = tiers[i]; break; }
    }
    if (CH == 0 && ws_size >= fixed) CH = 1;

    if (CH >= 1) {
        float* pbuf = (CH > 1) ? part : cols;   // CH==1: partial IS cols

        void* kargs[] = {
            (void*)&Iext, (void*)&V0, (void*)&m0, (void*)&h0, (void*)&n0,
            (void*)&s0, (void*)&W, (void*)&Ty, (void*)&Tp, (void*)&ctrl,
            (void*)&pbuf, (void*)&cols, (void*)&traj, (void*)&status,
            (void*)&CH, (void*)&out
        };
        hipError_t err = hipLaunchCooperativeKernel(
            (const void*)hh_coop_k, dim3(16, CH), dim3(256), kargs, 0, stream);

        if (err == hipSuccess) {
            // guard: exits in ~2us when certified; else R6 exchange fallback
            hipLaunchKernelGGL(hh_fallback_k, dim3(GRID_SIM), dim3(NPB), 0, stream,
                               Iext, V0, m0, h0, n0, s0, cols, Tp, ctrl,
                               (const int*)status, out);
        } else {
            // cooperative launch unavailable: proven R11 4-dispatch sequence
            (void)hipGetLastError();
            if (CH > 1) {
                hipLaunchKernelGGL(col_partial_k, dim3(NN / 256, CH), dim3(256), 0,
                                   stream, W, Ty, part, NN / CH);
                hipLaunchKernelGGL(col_reduce_k, dim3(6 * NN / 256), dim3(256), 0,
                                   stream, part, cols, CH);
            } else {
                hipLaunchKernelGGL(col_partial_k, dim3(NN / 256, 1), dim3(256), 0,
                                   stream, W, Ty, cols, NN);
            }
            hipLaunchKernelGGL(hh_probe_k, dim3(1), dim3(512), 0, stream,
                               Iext, V0, m0, h0, n0, s0, cols, ctrl, Tp, traj, status);
            hipLaunchKernelGGL(hh_sim_k, dim3(GRID_SIM), dim3(NPB), 0, stream,
                               Iext, V0, m0, h0, n0, s0, cols, Tp, ctrl, traj,
                               (const int*)status, out);
        }
    } else {
        hipLaunchKernelGGL(hh_sim_single, dim3(1), dim3(1024), 0, stream,
                           Iext, V0, m0, h0, n0, s0, (const float*)0, Tp, W, Ty, 1, out);
    }
}

// Round 14
// 211.847 us; speedup vs baseline: 1.7206x; 1.7206x over previous
//
#include <hip/hip_runtime.h>
#include <math.h>

#define NN 4096
#define CBLK 8               // worker blocks (fallback exchange protocol)
#define NPB (NN / CBLK)      // 512 threads per sim block
#define GRID_SIM 128         // candidate blocks; >=16 on some XCD by pigeonhole
#define SLOT_STRIDE 16       // ulls per line: 128 B -- ONE writer per line
#define CTRL_BYTES 4096
#define CTRL_ULLS 512
#define QPART_BYTES 12288    // up to 512 blocks x 6 floats
#define TRAJ_CAP 2040
#define TRAJ_BYTES 8192      // 2040 floats + status int + pad

typedef unsigned long long ull;

// ---------------------------------------------------------------------------
// Session ledger (structural facts, all HW-verified):
//  R1: multi-writer 128B lines -> L2 dirty thrash to HBM (2.65x). one writer/line.
//  R2: removing the per-step wave-parking barrier -> VMEM spin storm.
//  R4: sc0 asm = SE scope only; agent scope structural.
//  R5/R7: exchange line-count axis exhausted; 8 block lines optimal.
//  R6: 968us fallback champion; ~1 agent RTT/step, plumbing shadowed.
//  R8: data saturates (V rails uniformly, gates NaN -> V=0 forever);
//      probe+certificate+broadcast, absmax 0.
//  R9: probe NaN early-exit; ~38us per dispatch boundary measured.
//  R10: grid-parallel memory work in the 1-block probe = 8 GB/s disaster.
//  R11: 241us = 88us kernels + 4 boundaries. col_partial pattern-stuck at
//      ~2.6 TB/s regardless of CH/occupancy (axis dead).
//  R12: cooperative mega-kernel = 220us alone (grid.sync through IF +
//      coop launch overhead; phase A collapsed to 0.4 TB/s). Coop abandoned.
//  R13: cols NEVER materialized -- Qg is distributive over ROWS, so
//      col_partial emits per-block Qg partials to exclusive qpart slots
//      (plain stores, replay-safe; no atomics so no zero-init problem).
//      col_reduce deleted -> 3 dispatches. Fallback computes q from part.
//      [R13 bench was an infra failure ("container failed twice");
//       resubmitted unchanged -- no kernel-level signal to react to.]
// ---------------------------------------------------------------------------

// ---------------- DPP wave64 reduction helpers (HW-validated R2-R11) --------
template <int DC, int RM>
__device__ __forceinline__ float dppmov(float x) {
    return __int_as_float(
        __builtin_amdgcn_update_dpp(0, __float_as_int(x), DC, RM, 0xf, true));
}
__device__ __forceinline__ float wave_sum63(float x) {
    x += dppmov<0x111, 0xf>(x);   // row_shr:1
    x += dppmov<0x112, 0xf>(x);   // row_shr:2
    x += dppmov<0x114, 0xf>(x);   // row_shr:4
    x += dppmov<0x118, 0xf>(x);   // row_shr:8
    x += dppmov<0x142, 0xa>(x);   // row_bcast:15 -> rows 1,3
    x += dppmov<0x143, 0xc>(x);   // row_bcast:31 -> rows 2,3
    return x;                     // lane 63 holds the 64-lane sum
}
__device__ __forceinline__ float wave_max63(float x) {   // nonneg inputs
    x = fmaxf(x, dppmov<0x111, 0xf>(x));
    x = fmaxf(x, dppmov<0x112, 0xf>(x));
    x = fmaxf(x, dppmov<0x114, 0xf>(x));
    x = fmaxf(x, dppmov<0x118, 0xf>(x));
    x = fmaxf(x, dppmov<0x142, 0xa>(x));
    x = fmaxf(x, dppmov<0x143, 0xc>(x));
    return x;
}
__device__ __forceinline__ float dpp_sum8(float x) {
    x += dppmov<0x111, 0xf>(x);
    x += dppmov<0x112, 0xf>(x);
    x += dppmov<0x114, 0xf>(x);
    return x;
}
__device__ __forceinline__ float rdlane(float x, int l) {
    return __int_as_float(__builtin_amdgcn_readlane(__float_as_int(x), l));
}

// ---------------- col partial + per-block Qg contribution -------------------
// Qg[t] = sum_i sum_j s0[t][j] * W_masked[i][j] is distributive over rows,
// so each block dots its column-chunk sums a[t][r] with s0 and stores the
// 6-float contribution to an EXCLUSIVE qpart slot (plain stores --
// replay-safe, no zero-init needed). part is still written for the fallback.
__global__ __launch_bounds__(256) void col_partial_k(
    const float* __restrict__ W, const int* __restrict__ Ty,
    const float* __restrict__ s0,
    float* __restrict__ part, float* __restrict__ qpart, int chunkRows)
{
    const int tid = threadIdx.x;     // 0..255
    const int wv = tid >> 6;         // 0..3
    const int lane = tid & 63;
    const int j4 = (blockIdx.x * 64 + lane) * 4;
    const int c = blockIdx.y;
    const int flat = c * gridDim.x + blockIdx.x;
    const int rpw = chunkRows >> 2;  // rows per wave
    const size_t i0 = (size_t)c * (size_t)chunkRows + (size_t)wv * (size_t)rpw;

    float a[6][4];
#pragma unroll
    for (int t = 0; t < 6; ++t)
#pragma unroll
        for (int r = 0; r < 4; ++r) a[t][r] = 0.f;

#pragma unroll 4
    for (size_t i = i0; i < i0 + (size_t)rpw; ++i) {
        const size_t off = i * NN + j4;
        const float4 w = *(const float4*)(W + off);
        const int4 t = *(const int4*)(Ty + off);
        const float wv4[4] = { w.x, w.y, w.z, w.w };
        const int tv[4] = { t.x, t.y, t.z, t.w };
#pragma unroll
        for (int r = 0; r < 4; ++r) {
            a[0][r] += (tv[r] == 1) ? wv4[r] : 0.f;
            a[1][r] += (tv[r] == 2) ? wv4[r] : 0.f;
            a[2][r] += (tv[r] == 3) ? wv4[r] : 0.f;
            a[3][r] += (tv[r] == 4) ? wv4[r] : 0.f;
            a[4][r] += (tv[r] == 5) ? wv4[r] : 0.f;
            a[5][r] += (tv[r] == 6) ? wv4[r] : 0.f;
        }
    }

    __shared__ float red[3][64][25];   // 19.2 KB
    if (wv > 0) {
#pragma unroll
        for (int t = 0; t < 6; ++t)
#pragma unroll
            for (int r = 0; r < 4; ++r)
                red[wv - 1][lane][t * 4 + r] = a[t][r];
    }
    __syncthreads();
    if (wv == 0) {
#pragma unroll
        for (int w = 0; w < 3; ++w)
#pragma unroll
            for (int t = 0; t < 6; ++t)
#pragma unroll
                for (int r = 0; r < 4; ++r)
                    a[t][r] += red[w][lane][t * 4 + r];
        const size_t base = ((size_t)c * 6) * NN + (size_t)j4;
#pragma unroll
        for (int t = 0; t < 6; ++t)
            *(float4*)(part + base + (size_t)t * NN) =
                make_float4(a[t][0], a[t][1], a[t][2], a[t][3]);

        // per-block Qg contribution: dot a[t][*] with 0.1*s0[t][j4..j4+3]
#pragma unroll
        for (int t = 0; t < 6; ++t) {
            const float4 sv = *(const float4*)(s0 + (size_t)t * NN + j4);
            float qc = a[t][0] * sv.x + a[t][1] * sv.y
                     + a[t][2] * sv.z + a[t][3] * sv.w;
            qc = wave_sum63(qc);
            if (lane == 63) qpart[(size_t)flat * 6 + t] = 0.1f * qc;
        }
    }
}

// ---------------- shared device body: the serial uniform trajectory ---------
// EXACT R6/R11 gate arithmetic + certificate + NaN early exit (absmax 0 x3).
__device__ __forceinline__ int run_trajectory(
    const float* Qacc, float MIe, int steps, int lane,
    float* __restrict__ traj)
{
    float Qg[6];
#pragma unroll
    for (int t = 0; t < 6; ++t) Qg[t] = Qacc[t];
    const float CE1g = -70.0f * Qg[1];
    const float CE2g = -90.0f * Qg[2];

    const float tau[6] = { 2.0f, 5.0f, 10.0f, 100.0f, 50.0f, 30.0f };
    const float sgn[6] = { -1.0f, 1.0f, 1.0f, -1.0f, -1.0f, -1.0f };
    float dec[6], sD[6];
#pragma unroll
    for (int t = 0; t < 6; ++t) { dec[t] = 1.0f - 0.01f / tau[t]; sD[t] = sgn[t] * dec[t]; }

    float vu = 0.0f, m = 0.0f, h = 0.0f, n = 0.0f;
    int ok = 1;
    int kend = steps;

    for (int k = 0; k < steps; ++k) {
        float Cg = sD[5] * Qg[5];
        Cg = fmaf(sD[4], Qg[4], Cg);
        Cg = fmaf(sD[3], Qg[3], Cg);
        Cg = fmaf(sD[2], Qg[2], Cg);
        Cg = fmaf(sD[1], Qg[1], Cg);
        Cg = fmaf(sD[0], Qg[0], Cg);
        const float corrg = fmaf(sD[1], CE1g, sD[2] * CE2g);
        const float S = fmaf(vu, Cg, -corrg);

        const float v = vu;
        const float a1 = 2.5f - 0.1f * v;
        const float X = __expf(a1);
        const float am = a1 * __builtin_amdgcn_rcpf(X - 1.0f);
        const float bm = 4.0f * __expf(v * (-1.0f / 18.0f));
        const float ah = 0.07f * __expf(v * (-1.0f / 20.0f));
        const float bh = __builtin_amdgcn_rcpf(fmaf(1.6487212707001281f, X, 1.0f));
        const float a5 = 0.1f - 0.01f * v;
        const float an = a5 * __builtin_amdgcn_rcpf(fmaf(0.2231301601484298f, X, -1.0f));
        const float bn = 0.125f * __expf(v * (-1.0f / 80.0f));
        const float mm = m + 0.01f * (am * (1.0f - m) - bm * m);
        const float hh = h + 0.01f * (ah * (1.0f - h) - bh * h);
        const float nn = n + 0.01f * (an * (1.0f - n) - bn * n);
        m = mm; h = hh; n = nn;
        const float INa = ((120.0f * ((mm * mm) * mm)) * hh) * (v - 50.0f);
        const float n2 = nn * nn;
        const float IK = (36.0f * (n2 * n2)) * (v + 77.0f);
        const float IL = 0.3f * (v + 54.387f);
        const float Bu = ((0.0f - INa) - IK) - IL;
        const float t = vu + 0.01f * (Bu + S);

        float vn;
        if (t != t) {
            vn = 0.0f;                       // NaN -> nan_to_num -> 0 (exact)
        } else if (t > 1e30f) {
            vn = 100.0f;
        } else if (t < -1e30f) {
            vn = -100.0f;
        } else {
            const float slack = 0.01f * MIe + 0.01f +
                1e-4f * (fabsf(t) + fabsf(vu) +
                         0.01f * (fabsf(S) + fabsf(INa) + fabsf(IK)));
            if (t - slack > 100.0f)       vn = 100.0f;
            else if (t + slack < -100.0f) vn = -100.0f;
            else { ok = 0; break; }          // ambiguous -> exchange fallback
        }
        if (lane == 0) traj[k] = vn;
        vu = vn;

        // gate NaN persists forever -> all later V = 0 for every neuron. Exact.
        if ((m != m) || (h != h) || (n != n)) { kend = k + 1; break; }

#pragma unroll
        for (int t6 = 0; t6 < 6; ++t6) sD[t6] *= dec[t6];
    }
    if (ok) {
        for (int r = kend + lane; r < steps; r += 64) traj[r] = 0.0f;
    }
    return ok;
}

// ---------------- uniform-trajectory probe (qpart-fed) ----------------------
// 1 block. Zeroes ctrl (O(KB), fold-safe). Sums qpart (<=3072 floats) -> Qg.
// Uniformity + max|Ie| scan (80 KB). Serial trajectory + certificate.
__global__ __launch_bounds__(512) void hh_probe_k(
    const float* __restrict__ Iext, const float* __restrict__ V0,
    const float* __restrict__ m0, const float* __restrict__ h0,
    const float* __restrict__ n0, const float* __restrict__ qpart,
    int nblk, ull* __restrict__ ctrl, const int* __restrict__ Tp,
    float* __restrict__ traj, int* __restrict__ status)
{
#pragma clang fp contract(off)
    const int tid = threadIdx.x, wave = tid >> 6, lane = tid & 63;
    const int steps = Tp[0] * 100;

    if (tid < CTRL_ULLS) ctrl[tid] = 0ULL;

    __shared__ float red[8];
    __shared__ float sQg[6], sMIe, sBad;

    // Qg from per-block partials (static t indexing)
    for (int t = 0; t < 6; ++t) {
        float acc = 0.f;
        for (int i = tid; i < nblk; i += 512)
            acc += qpart[(size_t)i * 6 + t];
        acc = wave_sum63(acc);
        if (lane == 63) red[wave] = acc;
        __syncthreads();
        if (tid == 0) { float s = 0.f; for (int w = 0; w < 8; ++w) s += red[w]; sQg[t] = s; }
        __syncthreads();
    }

    // uniformity count + max|Ie|
    float bad = 0.f, mie = 0.f;
    for (int i = tid; i < NN; i += 512) {
        bad += (V0[i] != 0.f) ? 1.f : 0.f;
        bad += (m0[i] != 0.f) ? 1.f : 0.f;
        bad += (h0[i] != 0.f) ? 1.f : 0.f;
        bad += (n0[i] != 0.f) ? 1.f : 0.f;
        mie = fmaxf(mie, fabsf(Iext[i]));
    }
    bad = wave_sum63(bad);
    if (lane == 63) red[wave] = bad;
    __syncthreads();
    if (tid == 0) { float s = 0.f; for (int w = 0; w < 8; ++w) s += red[w]; sBad = s; }
    __syncthreads();
    mie = wave_max63(mie);
    if (lane == 63) red[wave] = mie;
    __syncthreads();
    if (tid == 0) { float s = 0.f; for (int w = 0; w < 8; ++w) s = fmaxf(s, red[w]); sMIe = s; }
    __syncthreads();

    if (sBad != 0.f || steps > TRAJ_CAP) {
        if (tid == 0) *status = 0;
        return;
    }
    if (wave != 0) return;

    const int ok = run_trajectory(sQg, sMIe, steps, lane, traj);
    if (lane == 0) *status = ok;
}

// ---------------- sim kernel: uniform broadcast OR R6-champion fallback -----
// Fallback computes q from part directly (c=0..CH-1 order -- bit-identical
// association to R11's cols); one-time ~us cost against its 968us runtime.
__global__ __launch_bounds__(NPB) void hh_sim_k(
    const float* __restrict__ Iext, const float* __restrict__ V0,
    const float* __restrict__ m0, const float* __restrict__ h0,
    const float* __restrict__ n0, const float* __restrict__ s0,
    const float* __restrict__ part, int CH, const int* __restrict__ Tp,
    ull* __restrict__ ctrl, const float* __restrict__ traj,
    const int* __restrict__ status, float* __restrict__ out)
{
#pragma clang fp contract(off)
    const int steps = Tp[0] * 100;
    const int tid = threadIdx.x;

    if (*status == 1) {
        // uniform trajectory verified: pure broadcast write, all 128 blocks
        for (int r = blockIdx.x; r < steps; r += GRID_SIM) {
            const float vv = traj[r];
            const float4 val = make_float4(vv, vv, vv, vv);
            float4* p = (float4*)(out + (size_t)r * NN + (size_t)tid * 8);
            p[0] = val; p[1] = val;
        }
        return;
    }

    // ---------------- R6 champion fallback (968us) --------------------------
    const int wave = tid >> 6;
    const int lane = tid & 63;

    __shared__ int sRank; __shared__ ull sKey, sChosen;
    __shared__ ull wtag[2][8];
    __shared__ float binit1[8], binit2[8];

    if (tid == 0) {
        // HW_REG_XCC_ID = hwreg 20, bits [3:0]  [measured: learn_hip m09]
        const int xid = (int)(__builtin_amdgcn_s_getreg((3 << 11) | 20)) & 7;
        const ull r = atomicAdd(&ctrl[(size_t)xid * SLOT_STRIDE], 1ULL);
        if (r == (ull)(CBLK - 1))
            atomicCAS(&ctrl[128], 0ULL, (ull)(xid + 1));
        ull ch;
        do {
            ch = __hip_atomic_load(&ctrl[128],
                                   __ATOMIC_RELAXED, __HIP_MEMORY_SCOPE_AGENT);
        } while (ch == 0ULL);
        sRank = (int)r; sKey = (ull)(xid + 1); sChosen = ch;
    }
    __syncthreads();
    const int b = sRank;
    if (sKey != sChosen || b >= CBLK) return;

    const int j = b * NPB + tid;
    ull* const slots = ctrl + 144;

    const float tau[6] = { 2.0f, 5.0f, 10.0f, 100.0f, 50.0f, 30.0f };
    const float sgn[6] = { -1.0f, 1.0f, 1.0f, -1.0f, -1.0f, -1.0f };
    float dec[6], sD[6];
#pragma unroll
    for (int t = 0; t < 6; ++t) { dec[t] = 1.0f - 0.01f / tau[t]; sD[t] = sgn[t]; }

    if (tid < 16) wtag[tid >> 3][tid & 7] = 0ULL;

    float V = V0[j], m = m0[j], h = h0[j], n = n0[j], Ie = Iext[j];
    float q[6];
#pragma unroll
    for (int t = 0; t < 6; ++t) {
        float s = 0.f;
        for (int c = 0; c < CH; ++c)
            s += part[(size_t)c * 6 * NN + (size_t)t * NN + j];
        q[t] = 0.1f * s0[(size_t)t * NN + j] * s;
    }

    {
        const float b1 = wave_sum63(q[1]);
        const float b2 = wave_sum63(q[2]);
        if (lane == 63) { binit1[wave] = b1; binit2[wave] = b2; }
    }
    __syncthreads();
    float CE1 = 0.f, CE2 = 0.f;
    if (wave == 0) {
        const float s1 = dpp_sum8((lane < 8) ? binit1[lane] : 0.f);
        const float s2 = dpp_sum8((lane < 8) ? binit2[lane] : 0.f);
        CE1 = -70.0f * rdlane(s1, 7);
        CE2 = -90.0f * rdlane(s2, 7);
    }
    __syncthreads();

#pragma unroll
    for (int t = 0; t < 6; ++t) sD[t] *= dec[t];
    float w6 = sD[5] * q[5];
    w6 = fmaf(sD[4], q[4], w6);
    w6 = fmaf(sD[3], q[3], w6);
    w6 = fmaf(sD[2], q[2], w6);
    w6 = fmaf(sD[1], q[1], w6);
    w6 = fmaf(sD[0], q[0], w6);
    float corr = fmaf(sD[1], CE1, sD[2] * CE2);

    float* op = out + j;

    for (int k = 0; k < steps; ++k) {
        const unsigned tag = (unsigned)(k + 1);
        const int par = (k & 1);

        const float x = w6 * V;
        const float xs = wave_sum63(x);
        if (lane == 63)
            __hip_atomic_store(&wtag[par][wave],
                               ((ull)tag << 32) | (ull)__float_as_uint(xs),
                               __ATOMIC_RELAXED, __HIP_MEMORY_SCOPE_WORKGROUP);
        __builtin_amdgcn_sched_barrier(0);

        if (wave == 0) {
            ull got = 0;
            if (lane < 8) {
                do {
                    got = __hip_atomic_load(&wtag[par][lane],
                                            __ATOMIC_RELAXED,
                                            __HIP_MEMORY_SCOPE_WORKGROUP);
                } while ((unsigned)(got >> 32) != tag);
            }
            float p = dpp_sum8((lane < 8) ? __uint_as_float((unsigned)got) : 0.f);
            if (lane == 7) {
                p = p - corr;
                const ull packed = ((ull)tag << 32) | (ull)__float_as_uint(p);
                __hip_atomic_store(&slots[(size_t)(par * CBLK + b) * SLOT_STRIDE],
                                   packed, __ATOMIC_RELAXED,
                                   __HIP_MEMORY_SCOPE_AGENT);
            }
        }
        __builtin_amdgcn_sched_barrier(0);
        __builtin_amdgcn_s_barrier();
        __builtin_amdgcn_sched_barrier(0);

        const float v = V;
        const float a1 = 2.5f - 0.1f * v;
        const float X = __expf(a1);
        const float am = a1 * __builtin_amdgcn_rcpf(X - 1.0f);
        const float bm = 4.0f * __expf(v * (-1.0f / 18.0f));
        const float ah = 0.07f * __expf(v * (-1.0f / 20.0f));
        const float bh = __builtin_amdgcn_rcpf(
            fmaf(1.6487212707001281f, X, 1.0f));
        const float a5 = 0.1f - 0.01f * v;
        const float an = a5 * __builtin_amdgcn_rcpf(
            fmaf(0.2231301601484298f, X, -1.0f));
        const float bn = 0.125f * __expf(v * (-1.0f / 80.0f));
        const float mm = m + 0.01f * (am * (1.0f - m) - bm * m);
        const float hh = h + 0.01f * (ah * (1.0f - h) - bh * h);
        const float nn = n + 0.01f * (an * (1.0f - n) - bn * n);
        m = mm; h = hh; n = nn;
        const float INa = ((120.0f * ((mm * mm) * mm)) * hh) * (v - 50.0f);
        const float n2 = nn * nn;
        const float IK = (36.0f * (n2 * n2)) * (v + 77.0f);
        const float IL = 0.3f * (v + 54.387f);
        const float base = ((Ie - INa) - IK) - IL;

#pragma unroll
        for (int t = 0; t < 6; ++t) sD[t] *= dec[t];
        float w6n = sD[5] * q[5];
        w6n = fmaf(sD[4], q[4], w6n);
        w6n = fmaf(sD[3], q[3], w6n);
        w6n = fmaf(sD[2], q[2], w6n);
        w6n = fmaf(sD[1], q[1], w6n);
        w6n = fmaf(sD[0], q[0], w6n);
        const float corrn = fmaf(sD[1], CE1, sD[2] * CE2);
        __builtin_amdgcn_sched_barrier(0);

        ull got = 0;
        if (lane < 8) {
            do {
                got = __hip_atomic_load(&slots[(size_t)(par * CBLK + lane) * SLOT_STRIDE],
                                        __ATOMIC_RELAXED, __HIP_MEMORY_SCOPE_AGENT);
            } while ((unsigned)(got >> 32) != tag);
        }
        float val = dpp_sum8((lane < 8) ? __uint_as_float((unsigned)got) : 0.f);
        const float S = rdlane(val, 7);

        const float u = V + 0.01f * (base + S);
        V = (u != u) ? 0.0f : fminf(fmaxf(u, -100.0f), 100.0f);
        *op = V; op += NN;
        w6 = w6n; corr = corrn;
    }
}

// ---------------- single-block fallback (tiny workspace) --------------------
__global__ __launch_bounds__(1024) void hh_sim_single(
    const float* __restrict__ Iext, const float* __restrict__ V0,
    const float* __restrict__ m0, const float* __restrict__ h0,
    const float* __restrict__ n0, const float* __restrict__ s0,
    const float* __restrict__ colsg, const int* __restrict__ Tp,
    const float* __restrict__ W, const int* __restrict__ Ty,
    int computeCols, float* __restrict__ out)
{
#pragma clang fp contract(off)
    const int tid = threadIdx.x;
    const int j0 = tid * 4;
    const int steps = Tp[0] * 100;

    const float tau[6] = { 2.0f, 5.0f, 10.0f, 100.0f, 50.0f, 30.0f };
    const float sgn[6] = { -1.0f, 1.0f, 1.0f, -1.0f, -1.0f, -1.0f };
    float dec[6], sD[6];
#pragma unroll
    for (int t = 0; t < 6; ++t) { dec[t] = 1.0f - 0.01f / tau[t]; sD[t] = sgn[t]; }

    float q[6][4];
    if (computeCols) {
        float acc[6][4];
#pragma unroll
        for (int t = 0; t < 6; ++t)
#pragma unroll
            for (int r = 0; r < 4; ++r) acc[t][r] = 0.f;
        for (int i = 0; i < NN; ++i) {
            const size_t rowo = (size_t)i * NN + (size_t)j0;
#pragma unroll
            for (int r = 0; r < 4; ++r) {
                const float w = W[rowo + r];
                const int t = Ty[rowo + r];
                acc[0][r] += (t == 1) ? w : 0.f;
                acc[1][r] += (t == 2) ? w : 0.f;
                acc[2][r] += (t == 3) ? w : 0.f;
                acc[3][r] += (t == 4) ? w : 0.f;
                acc[4][r] += (t == 5) ? w : 0.f;
                acc[5][r] += (t == 6) ? w : 0.f;
            }
        }
#pragma unroll
        for (int t = 0; t < 6; ++t)
#pragma unroll
            for (int r = 0; r < 4; ++r)
                q[t][r] = 0.1f * s0[(size_t)t * NN + j0 + r] * acc[t][r];
    } else {
#pragma unroll
        for (int t = 0; t < 6; ++t)
#pragma unroll
            for (int r = 0; r < 4; ++r)
                q[t][r] = 0.1f * s0[(size_t)t * NN + j0 + r] *
                          colsg[(size_t)t * NN + j0 + r];
    }

    float V[4], m[4], h[4], n[4], Ie[4];
#pragma unroll
    for (int r = 0; r < 4; ++r) {
        V[r] = V0[j0 + r]; m[r] = m0[j0 + r]; h[r] = h0[j0 + r];
        n[r] = n0[j0 + r]; Ie[r] = Iext[j0 + r];
    }

    __shared__ float wsum[2][16];
    __shared__ float Bsh[2];
    {
        float b1 = 0.f, b2 = 0.f;
#pragma unroll
        for (int r = 0; r < 4; ++r) { b1 += q[1][r]; b2 += q[2][r]; }
#pragma unroll
        for (int off = 32; off > 0; off >>= 1) {
            b1 += __shfl_down(b1, off);
            b2 += __shfl_down(b2, off);
        }
        if ((tid & 63) == 0) { wsum[0][tid >> 6] = b1; wsum[1][tid >> 6] = b2; }
        __syncthreads();
        if (tid == 0) {
            float s1 = 0.f, s2 = 0.f;
            for (int w2 = 0; w2 < 16; ++w2) { s1 += wsum[0][w2]; s2 += wsum[1][w2]; }
            Bsh[0] = s1; Bsh[1] = s2;
        }
        __syncthreads();
    }
    const float CE1 = -70.0f * Bsh[0];
    const float CE2 = -90.0f * Bsh[1];
    __syncthreads();

    for (int k = 0; k < steps; ++k) {
#pragma unroll
        for (int t = 0; t < 6; ++t) sD[t] *= dec[t];
        float p = 0.f;
#pragma unroll
        for (int r = 0; r < 4; ++r) {
            float w = sD[5] * q[5][r];
            w = fmaf(sD[4], q[4][r], w);
            w = fmaf(sD[3], q[3][r], w);
            w = fmaf(sD[2], q[2][r], w);
            w = fmaf(sD[1], q[1][r], w);
            w = fmaf(sD[0], q[0][r], w);
            p = fmaf(w, V[r], p);
        }
#pragma unroll
        for (int off = 32; off > 0; off >>= 1) p += __shfl_down(p, off);
        const int par = k & 1;
        if ((tid & 63) == 0) wsum[par][tid >> 6] = p;
        __syncthreads();
        float psum = 0.f;
#pragma unroll
        for (int w2 = 0; w2 < 16; ++w2) psum += wsum[par][w2];
        const float S = psum - fmaf(sD[1], CE1, sD[2] * CE2);

#pragma unroll
        for (int r = 0; r < 4; ++r) {
            const float v = V[r];
            const float Ipre = Ie[r] + S;
            const float a1 = 2.5f - 0.1f * v;
            const float X = __expf(a1);
            const float am = a1 * __builtin_amdgcn_rcpf(X - 1.0f);
            const float bm = 4.0f * __expf(v * (-1.0f / 18.0f));
            const float ah = 0.07f * __expf(v * (-1.0f / 20.0f));
            const float bh = __builtin_amdgcn_rcpf(fmaf(1.6487212707001281f, X, 1.0f));
            const float a5 = 0.1f - 0.01f * v;
            const float an = a5 * __builtin_amdgcn_rcpf(fmaf(0.2231301601484298f, X, -1.0f));
            const float bn = 0.125f * __expf(v * (-1.0f / 80.0f));
            const float mm = m[r] + 0.01f * (am * (1.0f - m[r]) - bm * m[r]);
            const float hh = h[r] + 0.01f * (ah * (1.0f - h[r]) - bh * h[r]);
            const float nn = n[r] + 0.01f * (an * (1.0f - n[r]) - bn * n[r]);
            m[r] = mm; h[r] = hh; n[r] = nn;
            const float INa = ((120.0f * ((mm * mm) * mm)) * hh) * (v - 50.0f);
            const float n2 = nn * nn;
            const float IK = (36.0f * (n2 * n2)) * (v + 77.0f);
            const float IL = 0.3f * (v + 54.387f);
            const float u = v + 0.01f * (((Ipre - INa) - IK) - IL);
            V[r] = (u != u) ? 0.0f : fminf(fmaxf(u, -100.0f), 100.0f);
        }
        *(float4*)(out + (size_t)k * NN + j0) =
            make_float4(V[0], V[1], V[2], V[3]);
    }
}

extern "C" void kernel_launch(void* const* d_in, const int* in_sizes, int n_in,
                              void* d_out, int out_size, void* d_ws, size_t ws_size,
                              hipStream_t stream)
{
    const float* Iext = (const float*)d_in[0];
    const float* W    = (const float*)d_in[1];
    const float* V0   = (const float*)d_in[2];
    const float* m0   = (const float*)d_in[3];
    const float* h0   = (const float*)d_in[4];
    const float* n0   = (const float*)d_in[5];
    const float* s0   = (const float*)d_in[6];
    const int*   Ty   = (const int*)d_in[7];
    const int*   Tp   = (const int*)d_in[8];
    float* out = (float*)d_out;

    // ws layout: [ctrl 4096][qpart 12288][traj+status 8192][part CH*6*NN f32]
    ull*   ctrl = (ull*)d_ws;
    float* qpart = (float*)((char*)d_ws + CTRL_BYTES);
    float* traj = (float*)((char*)qpart + QPART_BYTES);
    int*   status = (int*)(traj + TRAJ_CAP);
    float* part = (float*)((char*)traj + TRAJ_BYTES);

    int CH = 0;
    const int tiers[2] = { 32, 8 };
    const size_t fixed = CTRL_BYTES + QPART_BYTES + TRAJ_BYTES;
    for (int i = 0; i < 2; ++i) {
        const size_t need = fixed + (size_t)tiers[i] * 6 * NN * sizeof(float);
        if (ws_size >= need) { CH = tiers[i]; break; }
    }
    if (CH == 0 && ws_size >= fixed + (size_t)6 * NN * sizeof(float)) CH = 1;

    if (CH >= 1) {
        const int nblk = (NN / 256) * CH;   // 16 * CH
        hipLaunchKernelGGL(col_partial_k, dim3(NN / 256, CH), dim3(256), 0, stream,
                           W, Ty, s0, part, qpart, NN / CH);
        hipLaunchKernelGGL(hh_probe_k, dim3(1), dim3(512), 0, stream,
                           Iext, V0, m0, h0, n0, qpart, nblk, ctrl, Tp, traj, status);
        hipLaunchKernelGGL(hh_sim_k, dim3(GRID_SIM), dim3(NPB), 0, stream,
                           Iext, V0, m0, h0, n0, s0, part, CH, Tp, ctrl, traj,
                           (const int*)status, out);
    } else {
        hipLaunchKernelGGL(hh_sim_single, dim3(1), dim3(1024), 0, stream,
                           Iext, V0, m0, h0, n0, s0, (const float*)0, Tp, W, Ty, 1, out);
    }
}